// Round 2
// baseline (624.696 us; speedup 1.0000x reference)
//
#include <hip/hip_runtime.h>
#include <cstdint>
#include <cstddef>

#define ALPHA 0.2f
// N=8192, Fin=512, Fout=256 hard-coded per problem instance.

typedef __attribute__((ext_vector_type(8)))  short short8;   // 8 bf16 (4 VGPRs)
typedef __attribute__((ext_vector_type(16))) float f32x16;   // 32x32 MFMA acc

static __device__ __forceinline__ unsigned short f2bf(float x) {
  union { float f; unsigned u; } c; c.f = x;
  unsigned u = c.u;
  return (unsigned short)((u + 0x7FFFu + ((u >> 16) & 1u)) >> 16);  // RNE
}
static __device__ __forceinline__ float bf2f(unsigned short b) {
  union { unsigned u; float f; } c; c.u = ((unsigned)b) << 16;
  return c.f;
}

// ---------------- Kernel A: Whp = h @ W, K-split x2 (fp32) ------------------
// BM=128, BN=64, BK=32, 256 threads, 8x4/thread. grid 64*2*4=512 -> 2 blocks/CU.
__global__ __launch_bounds__(256, 2) void gemm1(const float* __restrict__ h,
                                                const float* __restrict__ W,
                                                float* __restrict__ Whp) {
  __shared__ float As[32][132];  // [k][m], padded
  __shared__ float Bs[32][64];   // [k][n]
  const int t = threadIdx.x;
  const int bid = blockIdx.x;
  const int nb = bid & 3, kb = (bid >> 2) & 1, mb = bid >> 3;
  const int m0 = mb * 128, n0 = nb * 64, kbase = kb * 256;
  const int ty = t >> 4, tx = t & 15;
  float acc[8][4];
#pragma unroll
  for (int i = 0; i < 8; i++)
#pragma unroll
    for (int j = 0; j < 4; j++) acc[i][j] = 0.f;

  for (int k0 = kbase; k0 < kbase + 256; k0 += 32) {
#pragma unroll
    for (int c = 0; c < 4; c++) {                 // stage A transposed
      int m = c * 32 + (t >> 3);
      int kq = (t & 7) * 4;
      float4 v = *(const float4*)&h[(size_t)(m0 + m) * 512 + k0 + kq];
      As[kq + 0][m] = v.x; As[kq + 1][m] = v.y;
      As[kq + 2][m] = v.z; As[kq + 3][m] = v.w;
    }
#pragma unroll
    for (int c = 0; c < 2; c++) {                 // stage B
      int k = c * 16 + (t >> 4);
      int n = (t & 15) * 4;
      *(float4*)&Bs[k][n] = *(const float4*)&W[(size_t)(k0 + k) * 256 + n0 + n];
    }
    __syncthreads();
#pragma unroll
    for (int k = 0; k < 32; k++) {
      float4 a0 = *(float4*)&As[k][ty * 8];
      float4 a1 = *(float4*)&As[k][ty * 8 + 4];
      float4 b  = *(float4*)&Bs[k][tx * 4];
      float av[8] = {a0.x, a0.y, a0.z, a0.w, a1.x, a1.y, a1.z, a1.w};
      float bv[4] = {b.x, b.y, b.z, b.w};
#pragma unroll
      for (int i = 0; i < 8; i++)
#pragma unroll
        for (int j = 0; j < 4; j++) acc[i][j] = fmaf(av[i], bv[j], acc[i][j]);
    }
    __syncthreads();
  }
  float* dst = Whp + (size_t)kb * (8192 * 256);
#pragma unroll
  for (int i = 0; i < 8; i++) {
    float4 v = {acc[i][0], acc[i][1], acc[i][2], acc[i][3]};
    *(float4*)&dst[(size_t)(m0 + ty * 8 + i) * 256 + n0 + tx * 4] = v;
  }
}

// ------- Kernel B: per-row f1,f2 dots, u/v pack, f2max via atomicMax --------
__global__ __launch_bounds__(256) void rowstats(const float* __restrict__ Whp,
                                                const float* __restrict__ a,
                                                float* __restrict__ f1,
                                                unsigned* __restrict__ uvpack,
                                                unsigned* __restrict__ f2key) {
  const int t = threadIdx.x;
  const int w = t >> 6, lane = t & 63;
  const int i = blockIdx.x * 4 + w;
  const size_t off = (size_t)i * 256 + lane * 4;
  float4 v0 = *(const float4*)&Whp[off];
  float4 v1 = *(const float4*)&Whp[(size_t)8192 * 256 + off];
  float4 wv = {v0.x + v1.x, v0.y + v1.y, v0.z + v1.z, v0.w + v1.w};
  float4 a1 = *(const float4*)&a[lane * 4];
  float4 a2 = *(const float4*)&a[256 + lane * 4];
  float s1 = wv.x * a1.x + wv.y * a1.y + wv.z * a1.z + wv.w * a1.w;
  float s2 = wv.x * a2.x + wv.y * a2.y + wv.z * a2.z + wv.w * a2.w;
#pragma unroll
  for (int o = 32; o; o >>= 1) { s1 += __shfl_xor(s1, o); s2 += __shfl_xor(s2, o); }
  if (lane == 0) {
    f1[i] = s1;
    float u = __expf(s2), v = __expf(ALPHA * s2);
    uvpack[i] = (unsigned)f2bf(u) | ((unsigned)f2bf(v) << 16);
    unsigned ub = __float_as_uint(s2);
    unsigned key = (ub & 0x80000000u) ? ~ub : (ub | 0x80000000u);  // order-preserving
    atomicMax(f2key, key);
  }
}

// ---------------- Kernel B2: WhT[c][i] bf16 transpose (coalesced) -----------
// grid 128 = 32 i-blocks(256) x 4 c-blocks(64)
__global__ __launch_bounds__(256) void transpose_k(const float* __restrict__ Whp,
                                                   unsigned short* __restrict__ WhT) {
  __shared__ unsigned short tile[64][264];   // stride 528B (16B mult)
  const int t = threadIdx.x;
  const int i0 = (blockIdx.x >> 2) * 256, c0 = (blockIdx.x & 3) * 64;
#pragma unroll
  for (int it = 0; it < 16; it++) {
    int i = it * 16 + (t >> 4);
    int cq = (t & 15) * 4;
    size_t off = (size_t)(i0 + i) * 256 + c0 + cq;
    float4 v0 = *(const float4*)&Whp[off];
    float4 v1 = *(const float4*)&Whp[(size_t)8192 * 256 + off];
    tile[cq + 0][i] = f2bf(v0.x + v1.x);
    tile[cq + 1][i] = f2bf(v0.y + v1.y);
    tile[cq + 2][i] = f2bf(v0.z + v1.z);
    tile[cq + 3][i] = f2bf(v0.w + v1.w);
  }
  __syncthreads();
  const int c = t >> 2, seg = t & 3;
#pragma unroll
  for (int k = 0; k < 8; k++) {
    int io = (k * 4 + seg) * 8;           // seg-interleave breaks bank aliasing
    *(uint4*)&WhT[(size_t)(c0 + c) * 8192 + i0 + io] = *(const uint4*)&tile[c][io];
  }
}

// ---------------- Kernel C: fused masked-softmax @ Wh -----------------------
// KSTEP=4 steps per barrier, double-buffered swizzled P tile, adj prefetch
// issued after the barrier so it overlaps the MFMA phase.
template <int JW>
__global__ __launch_bounds__(256, 4) void attn_main(const int* __restrict__ adj,
    const float* __restrict__ f1p, const unsigned* __restrict__ uvpack,
    const unsigned short* __restrict__ WhT, const unsigned* __restrict__ f2key,
    float* __restrict__ accP, float* __restrict__ lP) {
  constexpr int JS = 8192 / JW;
  constexpr int NSTEP = JW / 32;
  constexpr int KSTEP = 4;
  constexpr int G = NSTEP / KSTEP;
  __shared__ unsigned uvs[JW];
  __shared__ unsigned short Pt[2][32][KSTEP * 32];  // 16B-chunk XOR swizzle, no pad
  __shared__ float lred[32][8];
  const int t = threadIdx.x;
  const int bid = blockIdx.x;
  const int js = bid & (JS - 1);
  const int rb = bid / JS;
  const int r0 = rb * 32;
  const int jbase = js * JW;

#pragma unroll
  for (int c = 0; c < JW / 1024; c++) {
    int idx = c * 1024 + t * 4;
    *(uint4*)&uvs[idx] = *(const uint4*)&uvpack[jbase + idx];
  }

  const int r = t >> 3, q = t & 7;            // staging role: row r, j-chunk q
  unsigned key = *f2key;
  unsigned ub = (key & 0x80000000u) ? (key & 0x7FFFFFFFu) : ~key;
  const float F2max = __uint_as_float(ub);
  const float f1v = f1p[r0 + r];
  const float x = f1v + F2max;
  const float M = x > 0.f ? x : ALPHA * x;    // analytic per-row max bound
  const float Ai = __expf(f1v - M);
  const float Bi = __expf(ALPHA * f1v - M);
  const float Ui = __expf(-f1v);              // u_j > Ui <=> f1_i + f2_j > 0

  const int lane = t & 63, wave = t >> 6;
  const int am = lane & 31, asel = lane >> 5;
  f32x16 acc0 = {}, acc1 = {};
  float lpriv = 0.f;

  const int* adjp = adj + (size_t)(r0 + r) * 8192 + jbase + q * 4;
  const unsigned short* bp = WhT + (size_t)(wave * 64 + am) * 8192 + jbase + asel * 8;

  int4 av[KSTEP], avn[KSTEP] = {};
#pragma unroll
  for (int k = 0; k < KSTEP; k++) av[k] = *(const int4*)(adjp + k * 32);
  adjp += KSTEP * 32;

  __syncthreads();   // covers uvs preload

  for (int g = 0; g < G; g++) {
    const int buf = g & 1;
#pragma unroll
    for (int k = 0; k < KSTEP; k++) {
      uint4 uvq = *(const uint4*)&uvs[(g * KSTEP + k) * 32 + q * 4];
      const unsigned uv[4] = {uvq.x, uvq.y, uvq.z, uvq.w};
      const int ad[4] = {av[k].x, av[k].y, av[k].z, av[k].w};
      float wgt[4];
#pragma unroll
      for (int jj = 0; jj < 4; jj++) {
        float u = bf2f((unsigned short)(uv[jj] & 0xFFFFu));
        float v = bf2f((unsigned short)(uv[jj] >> 16));
        float wv = (u > Ui) ? Ai * u : Bi * v;  // exp(leaky(f1+f2)-M), factorized
        wgt[jj] = (ad[jj] > 0) ? wv : 0.f;
      }
      lpriv += (wgt[0] + wgt[1]) + (wgt[2] + wgt[3]);
      unsigned p0 = (unsigned)f2bf(wgt[0]) | ((unsigned)f2bf(wgt[1]) << 16);
      unsigned p1 = (unsigned)f2bf(wgt[2]) | ((unsigned)f2bf(wgt[3]) << 16);
      const int chunk = (k * 4 + (q >> 1)) ^ (r & 7);
      uint2 pw; pw.x = p0; pw.y = p1;
      *(uint2*)&Pt[buf][r][chunk * 8 + (q & 1) * 4] = pw;
    }
    __syncthreads();
    if (g + 1 < G) {   // prefetch AFTER barrier -> overlaps MFMA phase
#pragma unroll
      for (int k = 0; k < KSTEP; k++) avn[k] = *(const int4*)(adjp + k * 32);
    }
    adjp += KSTEP * 32;
#pragma unroll
    for (int k = 0; k < KSTEP; k++) {
#pragma unroll
      for (int hh = 0; hh < 2; hh++) {
        const int chunk = (k * 4 + hh * 2 + asel) ^ (am & 7);
        short8 afrag = *(const short8*)&Pt[buf][am][chunk * 8];
        const unsigned short* bcol = bp + (size_t)(g * KSTEP + k) * 32 + hh * 16;
        short8 bf0 = *(const short8*)bcol;
        short8 bf1 = *(const short8*)(bcol + (size_t)32 * 8192);
        acc0 = __builtin_amdgcn_mfma_f32_32x32x16_bf16(afrag, bf0, acc0, 0, 0, 0);
        acc1 = __builtin_amdgcn_mfma_f32_32x32x16_bf16(afrag, bf1, acc1, 0, 0, 0);
      }
    }
#pragma unroll
    for (int k = 0; k < KSTEP; k++) av[k] = avn[k];
  }

  const size_t base = (size_t)js * (8192 * 256);
#pragma unroll
  for (int reg = 0; reg < 16; reg++) {
    const int rowl = (reg & 3) + 8 * (reg >> 2) + 4 * asel;  // verified 32x32 C/D map
    const int col = wave * 64 + am;
    accP[base + (size_t)(r0 + rowl) * 256 + col] = acc0[reg];
    accP[base + (size_t)(r0 + rowl) * 256 + col + 32] = acc1[reg];
  }
  lred[r][q] = lpriv;
  __syncthreads();
  if (q == 0) {
    float s = 0.f;
#pragma unroll
    for (int k = 0; k < 8; k++) s += lred[r][k];
    lP[(size_t)js * 8192 + r0 + r] = s;
  }
}

// ---------------- Kernel D: combine slices, normalize, ELU ------------------
__global__ __launch_bounds__(256) void combine(const float* __restrict__ accP,
                                               const float* __restrict__ lP,
                                               float* __restrict__ out, int JS) {
  const int idx = (blockIdx.x * 256 + threadIdx.x) * 4;
  const int row = idx >> 8;
  float4 s = {0.f, 0.f, 0.f, 0.f};
  float l = 0.f;
  for (int j = 0; j < JS; j++) {
    float4 a = *(const float4*)&accP[(size_t)j * (8192 * 256) + idx];
    s.x += a.x; s.y += a.y; s.z += a.z; s.w += a.w;
    l += lP[(size_t)j * 8192 + row];
  }
  float inv = 1.0f / fmaxf(l, 1e-30f);
  float vv[4] = {s.x * inv, s.y * inv, s.z * inv, s.w * inv};
  float4 o;
  o.x = vv[0] > 0.f ? vv[0] : __expf(vv[0]) - 1.f;
  o.y = vv[1] > 0.f ? vv[1] : __expf(vv[1]) - 1.f;
  o.z = vv[2] > 0.f ? vv[2] : __expf(vv[2]) - 1.f;
  o.w = vv[3] > 0.f ? vv[3] : __expf(vv[3]) - 1.f;
  *(float4*)&out[idx] = o;
}

extern "C" void kernel_launch(void* const* d_in, const int* in_sizes, int n_in,
                              void* d_out, int out_size, void* d_ws, size_t ws_size,
                              hipStream_t stream) {
  const float* h  = (const float*)d_in[0];
  const int* adj  = (const int*)d_in[1];
  const float* W  = (const float*)d_in[2];
  const float* a  = (const float*)d_in[3];
  char* ws = (char*)d_ws;
  const size_t NF = (size_t)8192 * 256;

  // j-split by available workspace: 4 slices (grid 1024, 4 blocks/CU) needs
  // 32M accP + 4M WhT + smalls; else proven 2-slice layout (~21 MB).
  const int JS = (ws_size >= ((size_t)38 << 20)) ? 4 : 2;

  // ws layout: [0,16M) Whp (2 K-halves; dead after transpose/rowstats, then
  // reused as accP), [0, JS*8M) accP, then WhT 4M, then smalls.
  float* Whp           = (float*)ws;
  float* accP          = (float*)ws;
  const size_t accB    = (size_t)JS * NF * 4;
  unsigned short* WhT  = (unsigned short*)(ws + accB);
  char* sm             = ws + accB + ((size_t)4 << 20);
  float* f1            = (float*)sm;
  unsigned* uvpack     = (unsigned*)(sm + (32 << 10));
  unsigned* f2key      = (unsigned*)(sm + (64 << 10));
  float* lP            = (float*)(sm + (65 << 10));

  hipMemsetAsync(f2key, 0, 4, stream);
  gemm1<<<512, 256, 0, stream>>>(h, W, Whp);
  transpose_k<<<128, 256, 0, stream>>>(Whp, WhT);
  rowstats<<<2048, 256, 0, stream>>>(Whp, a, f1, uvpack, f2key);
  if (JS == 4)
    attn_main<2048><<<1024, 256, 0, stream>>>(adj, f1, uvpack, WhT, f2key, accP, lP);
  else
    attn_main<4096><<<512, 256, 0, stream>>>(adj, f1, uvpack, WhT, f2key, accP, lP);
  combine<<<2048, 256, 0, stream>>>(accP, lP, (float*)d_out, JS);
}